// Round 2
// baseline (5914.079 us; speedup 1.0000x reference)
//
#include <hip/hip_runtime.h>
#include <cstdint>
#include <cstddef>

#define BB 2
#define NN 16384
#define SS 4096
#define KK 32
#define FIN 16
#define R2C 0.01f
#define NCHUNK 256   // chunks = 64-slot ranges of the Morton-cell-sorted point array

typedef unsigned long long u64;

// ---------------- f32 DPP wave max (result valid at lane 63) ----------------
// update_dpp(old=own, src=own): invalid lanes keep own value -> idempotent max.
template <int CTRL>
__device__ __forceinline__ float fstep(float k) {
  const int n = __builtin_amdgcn_update_dpp(__float_as_int(k), __float_as_int(k),
                                            CTRL, 0xf, 0xf, false);
  return fmaxf(k, __int_as_float(n));
}
__device__ __forceinline__ float fchain(float k) {
  k = fstep<0x111>(k);  // row_shr:1
  k = fstep<0x112>(k);  // row_shr:2
  k = fstep<0x114>(k);  // row_shr:4
  k = fstep<0x118>(k);  // row_shr:8
  k = fstep<0x142>(k);  // row_bcast15
  k = fstep<0x143>(k);  // row_bcast31
  return k;             // lane 63 holds the wave max
}
template <int CTRL>
__device__ __forceinline__ void fstep2(float& a, float& b) {
  a = fstep<CTRL>(a);
  b = fstep<CTRL>(b);
}
__device__ __forceinline__ void fchain2(float& a, float& b) {
  fstep2<0x111>(a, b);
  fstep2<0x112>(a, b);
  fstep2<0x114>(a, b);
  fstep2<0x118>(a, b);
  fstep2<0x142>(a, b);
  fstep2<0x143>(a, b);
}
template <int CTRL>
__device__ __forceinline__ void fstep4(float& a, float& b, float& c, float& d) {
  a = fstep<CTRL>(a);
  b = fstep<CTRL>(b);
  c = fstep<CTRL>(c);
  d = fstep<CTRL>(d);
}
__device__ __forceinline__ void fchain4(float& a, float& b, float& c, float& d) {
  fstep4<0x111>(a, b, c, d);
  fstep4<0x112>(a, b, c, d);
  fstep4<0x114>(a, b, c, d);
  fstep4<0x118>(a, b, c, d);
  fstep4<0x142>(a, b, c, d);
  fstep4<0x143>(a, b, c, d);
}

// u32 DPP wave MIN (result at lane 63) — used once per iteration for the
// exact first-index (lowest original pid) tie-break.
template <int CTRL>
__device__ __forceinline__ unsigned int ustep(unsigned int k) {
  const unsigned int n = (unsigned int)__builtin_amdgcn_update_dpp(
      (int)k, (int)k, CTRL, 0xf, 0xf, false);
  return k < n ? k : n;
}
__device__ __forceinline__ unsigned int uchain(unsigned int k) {
  k = ustep<0x111>(k);
  k = ustep<0x112>(k);
  k = ustep<0x114>(k);
  k = ustep<0x118>(k);
  k = ustep<0x142>(k);
  k = ustep<0x143>(k);
  return k;
}

// ---------------- binning: counting-sort points into Morton-ordered cells ----------------
__device__ __forceinline__ int part3(int x) {  // 3 bits -> bits 0,3,6
  return (x & 1) | ((x & 2) << 2) | ((x & 4) << 4);
}

__global__ __launch_bounds__(512) void bin_kernel(const float* __restrict__ pos,
                                                  float4* __restrict__ cellpts,
                                                  float4* __restrict__ bboxLo,
                                                  float4* __restrict__ bboxHi) {
  const int b = blockIdx.x, t = threadIdx.x;
  const float* __restrict__ p = pos + (size_t)b * NN * 3;
  __shared__ int hist[512], sA[512], sB[512];
  hist[t] = 0;
  __syncthreads();
  int cidc[NN / 512];  // 32 per thread
#pragma unroll
  for (int m = 0; m < NN / 512; ++m) {
    const int i = m * 512 + t;
    const float x = p[i * 3 + 0], y = p[i * 3 + 1], z = p[i * 3 + 2];
    const int cx = min(7, (int)(x * 8.0f));
    const int cy = min(7, (int)(y * 8.0f));
    const int cz = min(7, (int)(z * 8.0f));
    const int cid = part3(cx) | (part3(cy) << 1) | (part3(cz) << 2);  // Morton
    cidc[m] = cid;
    atomicAdd(&hist[cid], 1);
  }
  __syncthreads();
  sA[t] = hist[t];
  __syncthreads();
  int* src = sA;
  int* dst = sB;
  for (int off = 1; off < 512; off <<= 1) {
    int v = src[t];
    if (t >= off) v += src[t - off];
    dst[t] = v;
    __syncthreads();
    int* tmp = src; src = dst; dst = tmp;
  }
  const int excl = (t == 0) ? 0 : src[t - 1];
  __syncthreads();
  hist[t] = excl;
  __syncthreads();
#pragma unroll
  for (int m = 0; m < NN / 512; ++m) {
    const int i = m * 512 + t;
    const int slot = atomicAdd(&hist[cidc[m]], 1);
    cellpts[(size_t)b * NN + slot] =
        make_float4(p[i * 3 + 0], p[i * 3 + 1], p[i * 3 + 2], __int_as_float(i));
  }
  __threadfence_block();
  __syncthreads();
  if (t < NCHUNK) {
    float4 lo = make_float4(1e30f, 1e30f, 1e30f, 0.0f);
    float4 hi = make_float4(-1e30f, -1e30f, -1e30f, 0.0f);
    for (int k = 0; k < 64; ++k) {
      const float4 q = cellpts[(size_t)b * NN + t * 64 + k];
      lo.x = fminf(lo.x, q.x); lo.y = fminf(lo.y, q.y); lo.z = fminf(lo.z, q.z);
      hi.x = fmaxf(hi.x, q.x); hi.y = fmaxf(hi.y, q.y); hi.z = fmaxf(hi.z, q.z);
    }
    bboxLo[b * NCHUNK + t] = lo;
    bboxHi[b * NCHUNK + t] = hi;
  }
}

// ---------------- FPS: one 1024-thread block (16 waves) per batch ----------------
// Exact AABB-pruned FPS (bit-identical). 256 chunks of 64 Morton-sorted points
// (the measured-best granularity). NEW in this round: chunk keys are plain f32
// chunk-max dmin (6-step fused DPP f32-max chain, ~1/3 the cost of the old f64
// packed-key chain). The winning pid is resolved LAZILY once per iteration in
// phase C: ballot for chunks whose key equals the global max, then an exact
// u32-min DPP chain over (dmin==max ? pid : ~0) within the (usually single)
// candidate chunk. This reproduces argmax first-index semantics bit-exactly:
// fmax over identical floats is exact, and min-pid over all tied lanes across
// all tied chunks equals the reference's lowest-original-index rule.
// Phase C now reads sDmin, which the NEXT iteration's phase B writes -> a
// second __syncthreads() protects it (cheap: all waves run identical phase C
// and arrive in lockstep). sKey is single-buffered: B writes it, barrier1, C
// reads it (and prefetches kOwn for next A), barrier2, repeat.
#define FPS_T 1024
#define FPS_NW 16

__global__ __launch_bounds__(FPS_T, 1) void fps_kernel(const float* __restrict__ pos,
                                                       const float4* __restrict__ cellpts,
                                                       const float4* __restrict__ bboxLo,
                                                       const float4* __restrict__ bboxHi,
                                                       int* __restrict__ idx_out) {
  const int b = blockIdx.x;
  const int t = threadIdx.x;
  const int wid = t >> 6;   // 0..15
  const int lane = t & 63;
  const float* __restrict__ p = pos + (size_t)b * NN * 3;
  const float4* __restrict__ cp = cellpts + (size_t)b * NN;

  __shared__ float sDmin[NN];           // 64 KB, indexed by sorted slot
  __shared__ unsigned short sPid[NN];   // 32 KB, original pid per sorted slot
  __shared__ float sKey[NCHUNK];        // 1 KB, f32 chunk-max dmin

  const int cown = ((lane & 15) << 4) | wid;  // owned chunk (real for lane<16)
  const int slotOwn = (wid << 4) | (lane & 15);
  const float4 blo = bboxLo[b * NCHUNK + cown];
  const float4 bhi = bboxHi[b * NCHUNK + cown];

  if (t < NCHUNK) sKey[t] = 1e30f;
  for (int s = t; s < NN; s += FPS_T) {
    sDmin[s] = 1e10f;
    sPid[s] = (unsigned short)__float_as_int(cp[s].w);
  }
  if (t == 0) idx_out[b * SS + 0] = 0;
  float lx = p[0], ly = p[1], lz = p[2];
  float kOwn = 1e30f;  // sKey[slotOwn], prefetched in phase C
  __syncthreads();

  for (int it = 1; it < SS; ++it) {
    // ---- A: test owned chunks (pure VALU, boxes + key in regs) ----
    const float ax = fmaxf(fmaxf(blo.x - lx, lx - bhi.x), 0.0f);
    const float ay = fmaxf(fmaxf(blo.y - ly, ly - bhi.y), 0.0f);
    const float az = fmaxf(fmaxf(blo.z - lz, lz - bhi.z), 0.0f);
    const float bl2 = ax * ax + ay * ay + az * az;
    // skip iff conservative lower bound exceeds chunk max dmin: then
    // min(dmin_j, d_j) == dmin_j exactly for every member (bit-exact skip).
    const bool act = (lane < 16) && !(bl2 * 0.99999f > kOwn);
    unsigned int mm = (unsigned int)__ballot(act);  // wave-uniform, low 16 bits

    // ---- B: quads of chunks, 8-deep register prefetch ----
    int ca0 = -1, ca1 = -1, ca2 = -1, ca3 = -1;
    int cb0 = -1, cb1 = -1, cb2 = -1, cb3 = -1;
    float4 Pa0, Pa1, Pa2, Pa3, Pb0, Pb1, Pb2, Pb3;
    float oa0 = 0, oa1 = 0, oa2 = 0, oa3 = 0, ob0 = 0, ob1 = 0, ob2 = 0, ob3 = 0;
#define POPC(cX, PX, oX)                                  \
    if (mm) {                                             \
      const int l = (int)__builtin_ctz(mm); mm &= mm - 1; \
      cX = (l << 4) | wid;                                \
      PX = cp[(size_t)((cX << 6) + lane)];                \
      oX = sDmin[(cX << 6) + lane];                       \
    }
#define DIST(PX, oX, dmX)                                                        \
    {                                                                            \
      const float dx = PX.x - lx, dy = PX.y - ly, dz = PX.z - lz;                \
      const float d = __fadd_rn(__fadd_rn(__fmul_rn(dx, dx), __fmul_rn(dy, dy)), \
                                __fmul_rn(dz, dz));                              \
      dmX = fminf(oX, d);                                                        \
    }
#define SLOT(c) ((((c) & 15) << 4) | ((c) >> 4))
    POPC(ca0, Pa0, oa0) POPC(ca1, Pa1, oa1) POPC(ca2, Pa2, oa2) POPC(ca3, Pa3, oa3)
    POPC(cb0, Pb0, ob0) POPC(cb1, Pb1, ob1) POPC(cb2, Pb2, ob2) POPC(cb3, Pb3, ob3)

    while (ca3 >= 0) {  // >=4 available: full quad (wave-uniform condition)
      float dm0, dm1, dm2, dm3;
      DIST(Pa0, oa0, dm0) DIST(Pa1, oa1, dm1) DIST(Pa2, oa2, dm2) DIST(Pa3, oa3, dm3)
      sDmin[(ca0 << 6) + lane] = dm0;
      sDmin[(ca1 << 6) + lane] = dm1;
      sDmin[(ca2 << 6) + lane] = dm2;
      sDmin[(ca3 << 6) + lane] = dm3;
      fchain4(dm0, dm1, dm2, dm3);
      if (lane == 63) {
        sKey[SLOT(ca0)] = dm0;
        sKey[SLOT(ca1)] = dm1;
        sKey[SLOT(ca2)] = dm2;
        sKey[SLOT(ca3)] = dm3;
      }
      ca0 = cb0; Pa0 = Pb0; oa0 = ob0;
      ca1 = cb1; Pa1 = Pb1; oa1 = ob1;
      ca2 = cb2; Pa2 = Pb2; oa2 = ob2;
      ca3 = cb3; Pa3 = Pb3; oa3 = ob3;
      cb0 = -1; cb1 = -1; cb2 = -1; cb3 = -1;
      POPC(cb0, Pb0, ob0) POPC(cb1, Pb1, ob1) POPC(cb2, Pb2, ob2) POPC(cb3, Pb3, ob3)
    }
    // tail: 0-3 chunks left in ca0..ca2 (wave-uniform branches)
    if (ca1 >= 0) {  // pair
      float dm0, dm1;
      DIST(Pa0, oa0, dm0) DIST(Pa1, oa1, dm1)
      sDmin[(ca0 << 6) + lane] = dm0;
      sDmin[(ca1 << 6) + lane] = dm1;
      fchain2(dm0, dm1);
      if (lane == 63) {
        sKey[SLOT(ca0)] = dm0;
        sKey[SLOT(ca1)] = dm1;
      }
      ca0 = ca2; Pa0 = Pa2; oa0 = oa2;
    }
    if (ca0 >= 0) {  // single
      float dm0;
      DIST(Pa0, oa0, dm0)
      sDmin[(ca0 << 6) + lane] = dm0;
      dm0 = fchain(dm0);
      if (lane == 63) sKey[SLOT(ca0)] = dm0;
    }
#undef POPC
#undef DIST
    __syncthreads();  // barrier1: B's sKey/sDmin writes visible to all

    // ---- C: global winner over 256 f32 chunk keys (all waves, redundant) ----
    kOwn = sKey[slotOwn];  // prefetch for next iteration's A (array stable here)
    const float k0 = sKey[lane];
    const float k1 = sKey[64 + lane];
    const float k2 = sKey[128 + lane];
    const float k3 = sKey[192 + lane];
    float bk = fmaxf(fmaxf(k0, k1), fmaxf(k2, k3));
    bk = fchain(bk);
    const float smax = __int_as_float(
        __builtin_amdgcn_readlane(__float_as_int(bk), 63));
    // candidate chunks: key == smax (normally exactly one)
    const u64 m0 = __ballot(k0 == smax);
    const u64 m1 = __ballot(k1 == smax);
    const u64 m2 = __ballot(k2 == smax);
    const u64 m3 = __ballot(k3 == smax);
    unsigned int best = 0xFFFFFFFFu;
#pragma unroll
    for (int g = 0; g < 4; ++g) {
      u64 m = (g == 0) ? m0 : (g == 1) ? m1 : (g == 2) ? m2 : m3;
      while (m) {  // wave-uniform loop over candidate chunks
        const int sl = (g << 6) + (int)__builtin_ctzll(m);
        m &= m - 1;
        const int c = ((sl & 15) << 4) | (sl >> 4);  // slot -> chunk id
        const float dv = sDmin[(c << 6) + lane];
        unsigned int pv = (dv == smax) ? (unsigned int)sPid[(c << 6) + lane]
                                       : 0xFFFFFFFFu;
        pv = uchain(pv);  // lane 63: lowest pid among tied lanes of this chunk
        const unsigned int cm =
            (unsigned int)__builtin_amdgcn_readlane((int)pv, 63);
        best = best < cm ? best : cm;
      }
    }
    const int fi = (int)best;  // exact argmax, first-index tie-break
    if (t == 0) idx_out[b * SS + it] = fi;
    // uniform (scalar) loads of winner coords
    lx = p[fi * 3 + 0];
    ly = p[fi * 3 + 1];
    lz = p[fi * 3 + 2];
    __syncthreads();  // barrier2: protect C's sDmin/sKey reads from next B
  }
}

// ---------------- Ball query: one wave per centroid ----------------
__global__ __launch_bounds__(256) void ballq_kernel(const float* __restrict__ pos,
                                                    const int* __restrict__ idx,
                                                    int* __restrict__ nbr,
                                                    int* __restrict__ cnt,
                                                    float* __restrict__ outC,
                                                    float* __restrict__ outB) {
  const int cs = blockIdx.x * 4 + (threadIdx.x >> 6);
  const int lane = threadIdx.x & 63;
  const int b = cs >> 12;           // S = 4096
  const int s = cs & (SS - 1);
  const float* __restrict__ p = pos + (size_t)b * NN * 3;
  const int ci = idx[cs];
  const float cx = p[ci * 3 + 0], cy = p[ci * 3 + 1], cz = p[ci * 3 + 2];
  // remove_self_loops: global src b*N+i == global dst b*S+s -> only b==0, i==s
  const int excl = (b == 0) ? s : -1;
  int count = 0;
  for (int tile = 0; tile < NN / 64; ++tile) {
    const int i = tile * 64 + lane;
    const float dx = cx - p[i * 3 + 0];
    const float dy = cy - p[i * 3 + 1];
    const float dz = cz - p[i * 3 + 2];
    const float d2 = __fadd_rn(__fadd_rn(__fmul_rn(dx, dx), __fmul_rn(dy, dy)), __fmul_rn(dz, dz));
    const bool in = (d2 <= R2C) && (i != excl);
    const unsigned long long m = __ballot(in);
    if (in) {
      const int rank = count + (int)__popcll(m & ((1ull << lane) - 1ull));
      if (rank < KK) nbr[cs * KK + rank] = i;
    }
    count += (int)__popcll(m);
    if (count >= KK) break;
  }
  if (lane == 0) {
    cnt[cs] = count < KK ? count : KK;
    outC[cs * 3 + 0] = cx;
    outC[cs * 3 + 1] = cy;
    outC[cs * 3 + 2] = cz;
    outB[cs] = (float)b;
  }
}

// ---------------- MLP + max: one block (128 thr) per centroid ----------------
#define EE 33
__global__ __launch_bounds__(128) void mlp_kernel(const float* __restrict__ x,
                                                  const float* __restrict__ pos,
                                                  const int* __restrict__ nbr,
                                                  const int* __restrict__ cnt,
                                                  const float* __restrict__ W1,
                                                  const float* __restrict__ b1,
                                                  const float* __restrict__ W2,
                                                  const float* __restrict__ b2,
                                                  const float* __restrict__ W3,
                                                  const float* __restrict__ b3,
                                                  const float* __restrict__ outC,
                                                  float* __restrict__ outX) {
  __shared__ float sF[EE][20];
  __shared__ float sH1[EE][64];
  __shared__ float sH2[EE][64];
  __shared__ int sValid[EE];

  const int cs = blockIdx.x;
  const int tid = threadIdx.x;
  const int b = cs >> 12;
  const int c = tid & 63;
  const int half = tid >> 6;

  float w1c[19], w2c[64], w3c[64];
#pragma unroll
  for (int k = 0; k < 19; ++k) w1c[k] = W1[k * 64 + c];
#pragma unroll
  for (int k = 0; k < 64; ++k) w2c[k] = W2[k * 64 + c];
#pragma unroll
  for (int k = 0; k < 64; ++k) w3c[k] = W3[k * 128 + tid];
  const float b1c = b1[c], b2c = b2[c], b3c = b3[tid];

  if (tid < EE) {
    const float ccx = outC[cs * 3 + 0], ccy = outC[cs * 3 + 1], ccz = outC[cs * 3 + 2];
    int row;
    bool valid;
    if (tid < KK) {
      const int cn = cnt[cs];
      valid = tid < cn;
      const int j = valid ? nbr[cs * KK + tid] : 0;
      row = b * NN + j;
    } else {
      // PyG add_self_loops quirk: src is flat point index dflat = b*S+s = cs
      valid = true;
      row = cs;
    }
    for (int f = 0; f < FIN; ++f) sF[tid][f] = x[(size_t)row * FIN + f];
    sF[tid][16] = pos[(size_t)row * 3 + 0] - ccx;
    sF[tid][17] = pos[(size_t)row * 3 + 1] - ccy;
    sF[tid][18] = pos[(size_t)row * 3 + 2] - ccz;
    sValid[tid] = valid ? 1 : 0;
  }
  __syncthreads();
  for (int e = half; e < EE; e += 2) {
    float acc = b1c;
#pragma unroll
    for (int k = 0; k < 19; ++k) acc += sF[e][k] * w1c[k];
    sH1[e][c] = fmaxf(acc, 0.0f);
  }
  __syncthreads();
  for (int e = half; e < EE; e += 2) {
    float acc = b2c;
#pragma unroll
    for (int k = 0; k < 64; ++k) acc += sH1[e][k] * w2c[k];
    sH2[e][c] = fmaxf(acc, 0.0f);
  }
  __syncthreads();
  float mx = -1e30f;
  for (int e = 0; e < EE; ++e) {
    if (sValid[e]) {
      float acc = b3c;
#pragma unroll
      for (int k = 0; k < 64; ++k) acc += sH2[e][k] * w3c[k];
      mx = fmaxf(mx, acc);
    }
  }
  outX[(size_t)cs * 128 + tid] = mx;
}

extern "C" void kernel_launch(void* const* d_in, const int* in_sizes, int n_in,
                              void* d_out, int out_size, void* d_ws, size_t ws_size,
                              hipStream_t stream) {
  const float* x = (const float*)d_in[0];
  const float* pos = (const float*)d_in[1];
  const float* W1 = (const float*)d_in[3];
  const float* b1 = (const float*)d_in[4];
  const float* W2 = (const float*)d_in[5];
  const float* b2 = (const float*)d_in[6];
  const float* W3 = (const float*)d_in[7];
  const float* b3 = (const float*)d_in[8];

  float* out = (float*)d_out;
  float* outX = out;                               // [B*S,128]
  float* outC = out + (size_t)BB * SS * 128;       // [B*S,3]
  float* outB = outC + (size_t)BB * SS * 3;        // [B*S]

  float4* cellpts = (float4*)d_ws;                         // BB*NN float4
  float4* bboxLo = cellpts + (size_t)BB * NN;              // BB*256
  float4* bboxHi = bboxLo + BB * NCHUNK;                   // BB*256
  int* idx = (int*)(bboxHi + BB * NCHUNK);                 // BB*SS
  int* nbr = idx + BB * SS;                                // BB*SS*KK
  int* cnt = nbr + (size_t)BB * SS * KK;                   // BB*SS

  hipLaunchKernelGGL(bin_kernel, dim3(BB), dim3(512), 0, stream, pos, cellpts, bboxLo, bboxHi);
  hipLaunchKernelGGL(fps_kernel, dim3(BB), dim3(FPS_T), 0, stream, pos, cellpts, bboxLo, bboxHi, idx);
  hipLaunchKernelGGL(ballq_kernel, dim3(BB * SS / 4), dim3(256), 0, stream,
                     pos, idx, nbr, cnt, outC, outB);
  hipLaunchKernelGGL(mlp_kernel, dim3(BB * SS), dim3(128), 0, stream,
                     x, pos, nbr, cnt, W1, b1, W2, b2, W3, b3, outC, outX);
}

// Round 3
// 4765.355 us; speedup vs baseline: 1.2411x; 1.2411x over previous
//
#include <hip/hip_runtime.h>
#include <cstdint>
#include <cstddef>

#define BB 2
#define NN 16384
#define SS 4096
#define KK 32
#define FIN 16
#define R2C 0.01f
#define NCHUNK 256   // chunks = 64-slot ranges of the Morton-cell-sorted point array

typedef unsigned long long u64;

// ---------------- fused 32-bit DPP chains (1 instr/step after GCNDPPCombine) ----
// update_dpp(old=own, src=own): shifted-in lanes keep own value -> idempotent.
template <int CTRL>
__device__ __forceinline__ float fstep(float k) {
  const int n = __builtin_amdgcn_update_dpp(__float_as_int(k), __float_as_int(k),
                                            CTRL, 0xf, 0xf, false);
  return fmaxf(k, __int_as_float(n));  // -> v_max_f32_dpp
}
__device__ __forceinline__ float fchain(float k) {
  k = fstep<0x111>(k);  // row_shr:1
  k = fstep<0x112>(k);  // row_shr:2
  k = fstep<0x114>(k);  // row_shr:4
  k = fstep<0x118>(k);  // row_shr:8
  k = fstep<0x142>(k);  // row_bcast15
  k = fstep<0x143>(k);  // row_bcast31
  return k;             // lane 63 holds the wave max
}
template <int CTRL>
__device__ __forceinline__ unsigned int ustep(unsigned int k) {
  const unsigned int n = (unsigned int)__builtin_amdgcn_update_dpp(
      (int)k, (int)k, CTRL, 0xf, 0xf, false);
  return k > n ? k : n;  // -> v_max_u32_dpp
}
__device__ __forceinline__ unsigned int uchain(unsigned int k) {
  k = ustep<0x111>(k);
  k = ustep<0x112>(k);
  k = ustep<0x114>(k);
  k = ustep<0x118>(k);
  k = ustep<0x142>(k);
  k = ustep<0x143>(k);
  return k;             // lane 63 holds the wave max
}

// ---------------- f64-packed-key DPP wave max (phase C only, proven r0) --------
// keys are (f32bits(dmin)<<32)|rank: high bit 0 -> positive finite double, so
// f64 ordering == u64 ordering; one v_max_f64 replaces cmp+cndmask per step.
template <int CTRL>
__device__ __forceinline__ double kstep64(double k) {
  const u64 kb = (u64)__double_as_longlong(k);
  const int lo = (int)(unsigned int)kb;
  const int hi = (int)(unsigned int)(kb >> 32);
  const int nlo = __builtin_amdgcn_update_dpp(lo, lo, CTRL, 0xf, 0xf, false);
  const int nhi = __builtin_amdgcn_update_dpp(hi, hi, CTRL, 0xf, 0xf, false);
  const double nk = __longlong_as_double(
      (long long)(((u64)(unsigned int)nhi << 32) | (unsigned int)nlo));
  return fmax(k, nk);
}
__device__ __forceinline__ double kchain64(double k) {
  k = kstep64<0x111>(k);
  k = kstep64<0x112>(k);
  k = kstep64<0x114>(k);
  k = kstep64<0x118>(k);
  k = kstep64<0x142>(k);
  k = kstep64<0x143>(k);
  return k;  // lane 63 holds the wave max
}

// ---------------- binning: counting-sort points into Morton-ordered cells ----------------
__device__ __forceinline__ int part3(int x) {  // 3 bits -> bits 0,3,6
  return (x & 1) | ((x & 2) << 2) | ((x & 4) << 4);
}

__global__ __launch_bounds__(512) void bin_kernel(const float* __restrict__ pos,
                                                  float4* __restrict__ cellpts,
                                                  float4* __restrict__ bboxLo,
                                                  float4* __restrict__ bboxHi) {
  const int b = blockIdx.x, t = threadIdx.x;
  const float* __restrict__ p = pos + (size_t)b * NN * 3;
  __shared__ int hist[512], sA[512], sB[512];
  hist[t] = 0;
  __syncthreads();
  int cidc[NN / 512];  // 32 per thread
#pragma unroll
  for (int m = 0; m < NN / 512; ++m) {
    const int i = m * 512 + t;
    const float x = p[i * 3 + 0], y = p[i * 3 + 1], z = p[i * 3 + 2];
    const int cx = min(7, (int)(x * 8.0f));
    const int cy = min(7, (int)(y * 8.0f));
    const int cz = min(7, (int)(z * 8.0f));
    const int cid = part3(cx) | (part3(cy) << 1) | (part3(cz) << 2);  // Morton
    cidc[m] = cid;
    atomicAdd(&hist[cid], 1);
  }
  __syncthreads();
  sA[t] = hist[t];
  __syncthreads();
  int* src = sA;
  int* dst = sB;
  for (int off = 1; off < 512; off <<= 1) {
    int v = src[t];
    if (t >= off) v += src[t - off];
    dst[t] = v;
    __syncthreads();
    int* tmp = src; src = dst; dst = tmp;
  }
  const int excl = (t == 0) ? 0 : src[t - 1];
  __syncthreads();
  hist[t] = excl;
  __syncthreads();
#pragma unroll
  for (int m = 0; m < NN / 512; ++m) {
    const int i = m * 512 + t;
    const int slot = atomicAdd(&hist[cidc[m]], 1);
    cellpts[(size_t)b * NN + slot] =
        make_float4(p[i * 3 + 0], p[i * 3 + 1], p[i * 3 + 2], __int_as_float(i));
  }
  __threadfence_block();
  __syncthreads();
  if (t < NCHUNK) {
    float4 lo = make_float4(1e30f, 1e30f, 1e30f, 0.0f);
    float4 hi = make_float4(-1e30f, -1e30f, -1e30f, 0.0f);
    for (int k = 0; k < 64; ++k) {
      const float4 q = cellpts[(size_t)b * NN + t * 64 + k];
      lo.x = fminf(lo.x, q.x); lo.y = fminf(lo.y, q.y); lo.z = fminf(lo.z, q.z);
      hi.x = fmaxf(hi.x, q.x); hi.y = fmaxf(hi.y, q.y); hi.z = fmaxf(hi.z, q.z);
    }
    bboxLo[b * NCHUNK + t] = lo;
    bboxHi[b * NCHUNK + t] = hi;
  }
}

// ---------------- FPS: one 1024-thread block (16 waves) per batch ----------------
// Exact AABB-pruned FPS, r0 sync structure (ONE barrier/iter, double-buffered
// u64 keys, proven phase A + phase C). NEW: phase B is a compile-time-unrolled
// scalar-predicated loop over the wave's 16 owned chunks with coords + rank in
// REGISTERS (no per-iteration global loads, no POPC addressing), and the chunk
// reduction is two FUSED 32-bit DPP chains (v_max_f32_dpp on dmin, then
// v_max_u32_dpp on rank for tied lanes) instead of the unfusable 18-instr
// v_max_f64 chain. Key format (dminbits<<32)|((16383-pid)<<14|chunk<<6|lane)
// preserves exact (dmin desc, pid asc) lexicographic order: C's f64 chain and
// tie-break semantics are bit-identical to r0; decode fi = 16383-(lo>>14).
#define FPS_T 1024
#define FPS_NW 16

__global__ __launch_bounds__(FPS_T, 1) void fps_kernel(const float* __restrict__ pos,
                                                       const float4* __restrict__ cellpts,
                                                       const float4* __restrict__ bboxLo,
                                                       const float4* __restrict__ bboxHi,
                                                       int* __restrict__ idx_out) {
  const int b = blockIdx.x;
  const int t = threadIdx.x;
  const int wid = t >> 6;   // 0..15
  const int lane = t & 63;
  const float* __restrict__ p = pos + (size_t)b * NN * 3;
  const float4* __restrict__ cp = cellpts + (size_t)b * NN;

  __shared__ float sDmin[NN];      // 64 KB, indexed by sorted slot
  __shared__ u64 sKey[2][NCHUNK];  // double-buffered packed chunk keys (4 KB)

  const int cown = ((lane & 15) << 4) | wid;  // owned chunk (real for lane<16)
  const int slotOwn = (wid << 4) | (lane & 15);
  const float4 blo = bboxLo[b * NCHUNK + cown];
  const float4 bhi = bboxHi[b * NCHUNK + cown];

  // preload this wave's 16 owned chunks: coords + encoded rank, in registers.
  // rank = (16383-pid)<<14 | chunk<<6 | lane : u64-key low word. Higher rank
  // == lower pid; chunk/lane bits only disambiguate (pids are unique).
  float px[16], py[16], pz[16];
  unsigned int rp[16];
#pragma unroll
  for (int cc = 0; cc < 16; ++cc) {
    const int c = (cc << 4) | wid;
    const float4 q = cp[(size_t)((c << 6) + lane)];
    px[cc] = q.x; py[cc] = q.y; pz[cc] = q.z;
    const unsigned int pid = (unsigned int)__float_as_int(q.w);
    rp[cc] = ((16383u - pid) << 14) | ((unsigned int)c << 6) | (unsigned int)lane;
  }

  const u64 initKey = ((u64)(unsigned int)__float_as_int(1e30f) << 32);
  if (t < NCHUNK) sKey[0][t] = initKey;
  for (int s = t; s < NN; s += FPS_T) sDmin[s] = 1e10f;
  if (t == 0) idx_out[b * SS + 0] = 0;
  float lx = p[0], ly = p[1], lz = p[2];
  u64 kOwn = initKey;  // sKey[buf][slotOwn], carried across iterations
  __syncthreads();

  int buf = 0;
  // dmin addr for owned chunk cc: index = cc*1024 + wid*64 + lane (static offsets)
  float* const sD0 = &sDmin[(wid << 6) + lane];

  for (int it = 1; it < SS; ++it) {
    // ---- A: test owned chunks (pure VALU, boxes + key in regs) ----
    const float mvOwn = __int_as_float((int)(unsigned int)(kOwn >> 32));
    const float ax = fmaxf(fmaxf(blo.x - lx, lx - bhi.x), 0.0f);
    const float ay = fmaxf(fmaxf(blo.y - ly, ly - bhi.y), 0.0f);
    const float az = fmaxf(fmaxf(blo.z - lz, lz - bhi.z), 0.0f);
    const float bl2 = ax * ax + ay * ay + az * az;
    // skip iff conservative lower bound exceeds chunk max dmin: then
    // min(dmin_j, d_j) == dmin_j exactly for every member (bit-exact skip).
    const bool act = (lane < 16) && !(bl2 * 0.99999f > mvOwn);
    if ((lane < 16) && !act) sKey[buf ^ 1][slotOwn] = kOwn;  // carry (stride-1)
    const unsigned int mm = (unsigned int)__ballot(act);  // uniform, low 16 bits

    // ---- B: predicated unroll over the 16 owned chunks, all data in regs ----
#pragma unroll
    for (int cc = 0; cc < 16; ++cc) {
      if (mm & (1u << cc)) {  // wave-uniform scalar branch
        const float od = sD0[cc * 1024];
        const float dx = px[cc] - lx, dy = py[cc] - ly, dz = pz[cc] - lz;
        const float d = __fadd_rn(__fadd_rn(__fmul_rn(dx, dx), __fmul_rn(dy, dy)),
                                  __fmul_rn(dz, dz));
        const float nd = fminf(od, d);
        sD0[cc * 1024] = nd;
        const float cm = fchain(nd);  // lane 63: chunk max
        const float cm_s = __int_as_float(
            __builtin_amdgcn_readlane(__float_as_int(cm), 63));
        unsigned int tt = (nd == cm_s) ? rp[cc] : 0u;  // rank of tied lanes
        tt = uchain(tt);  // lane 63: max rank == lowest pid among tied
        if (lane == 63) {
          const u64 key = ((u64)(unsigned int)__float_as_int(cm) << 32) | tt;
          sKey[buf ^ 1][(wid << 4) | cc] = key;
        }
      }
    }
    __syncthreads();  // the ONLY barrier per iteration
    buf ^= 1;

    // ---- C: global winner over 256 packed chunk keys (all waves, redundant) ----
    kOwn = sKey[buf][slotOwn];  // hoisted for next iteration's A (stride-1)
    double bk = 0.0;            // all keys are positive doubles
#pragma unroll
    for (int g = 0; g < 4; ++g) {
      const double k = __longlong_as_double((long long)sKey[buf][g * 64 + lane]);
      bk = fmax(bk, k);
    }
    bk = kchain64(bk);
    const unsigned int lo63 = (unsigned int)__builtin_amdgcn_readlane(
        (int)(unsigned int)(u64)__double_as_longlong(bk), 63);
    const int fi = 16383 - (int)(lo63 >> 14);  // decode winning original index
    if (t == 0) idx_out[b * SS + it] = fi;
    // uniform (scalar) loads of winner coords
    lx = p[fi * 3 + 0];
    ly = p[fi * 3 + 1];
    lz = p[fi * 3 + 2];
  }
}

// ---------------- Ball query: one wave per centroid ----------------
__global__ __launch_bounds__(256) void ballq_kernel(const float* __restrict__ pos,
                                                    const int* __restrict__ idx,
                                                    int* __restrict__ nbr,
                                                    int* __restrict__ cnt,
                                                    float* __restrict__ outC,
                                                    float* __restrict__ outB) {
  const int cs = blockIdx.x * 4 + (threadIdx.x >> 6);
  const int lane = threadIdx.x & 63;
  const int b = cs >> 12;           // S = 4096
  const int s = cs & (SS - 1);
  const float* __restrict__ p = pos + (size_t)b * NN * 3;
  const int ci = idx[cs];
  const float cx = p[ci * 3 + 0], cy = p[ci * 3 + 1], cz = p[ci * 3 + 2];
  // remove_self_loops: global src b*N+i == global dst b*S+s -> only b==0, i==s
  const int excl = (b == 0) ? s : -1;
  int count = 0;
  for (int tile = 0; tile < NN / 64; ++tile) {
    const int i = tile * 64 + lane;
    const float dx = cx - p[i * 3 + 0];
    const float dy = cy - p[i * 3 + 1];
    const float dz = cz - p[i * 3 + 2];
    const float d2 = __fadd_rn(__fadd_rn(__fmul_rn(dx, dx), __fmul_rn(dy, dy)), __fmul_rn(dz, dz));
    const bool in = (d2 <= R2C) && (i != excl);
    const unsigned long long m = __ballot(in);
    if (in) {
      const int rank = count + (int)__popcll(m & ((1ull << lane) - 1ull));
      if (rank < KK) nbr[cs * KK + rank] = i;
    }
    count += (int)__popcll(m);
    if (count >= KK) break;
  }
  if (lane == 0) {
    cnt[cs] = count < KK ? count : KK;
    outC[cs * 3 + 0] = cx;
    outC[cs * 3 + 1] = cy;
    outC[cs * 3 + 2] = cz;
    outB[cs] = (float)b;
  }
}

// ---------------- MLP + max: one block (128 thr) per centroid ----------------
#define EE 33
__global__ __launch_bounds__(128) void mlp_kernel(const float* __restrict__ x,
                                                  const float* __restrict__ pos,
                                                  const int* __restrict__ nbr,
                                                  const int* __restrict__ cnt,
                                                  const float* __restrict__ W1,
                                                  const float* __restrict__ b1,
                                                  const float* __restrict__ W2,
                                                  const float* __restrict__ b2,
                                                  const float* __restrict__ W3,
                                                  const float* __restrict__ b3,
                                                  const float* __restrict__ outC,
                                                  float* __restrict__ outX) {
  __shared__ float sF[EE][20];
  __shared__ float sH1[EE][64];
  __shared__ float sH2[EE][64];
  __shared__ int sValid[EE];

  const int cs = blockIdx.x;
  const int tid = threadIdx.x;
  const int b = cs >> 12;
  const int c = tid & 63;
  const int half = tid >> 6;

  float w1c[19], w2c[64], w3c[64];
#pragma unroll
  for (int k = 0; k < 19; ++k) w1c[k] = W1[k * 64 + c];
#pragma unroll
  for (int k = 0; k < 64; ++k) w2c[k] = W2[k * 64 + c];
#pragma unroll
  for (int k = 0; k < 64; ++k) w3c[k] = W3[k * 128 + tid];
  const float b1c = b1[c], b2c = b2[c], b3c = b3[tid];

  if (tid < EE) {
    const float ccx = outC[cs * 3 + 0], ccy = outC[cs * 3 + 1], ccz = outC[cs * 3 + 2];
    int row;
    bool valid;
    if (tid < KK) {
      const int cn = cnt[cs];
      valid = tid < cn;
      const int j = valid ? nbr[cs * KK + tid] : 0;
      row = b * NN + j;
    } else {
      // PyG add_self_loops quirk: src is flat point index dflat = b*S+s = cs
      valid = true;
      row = cs;
    }
    for (int f = 0; f < FIN; ++f) sF[tid][f] = x[(size_t)row * FIN + f];
    sF[tid][16] = pos[(size_t)row * 3 + 0] - ccx;
    sF[tid][17] = pos[(size_t)row * 3 + 1] - ccy;
    sF[tid][18] = pos[(size_t)row * 3 + 2] - ccz;
    sValid[tid] = valid ? 1 : 0;
  }
  __syncthreads();
  for (int e = half; e < EE; e += 2) {
    float acc = b1c;
#pragma unroll
    for (int k = 0; k < 19; ++k) acc += sF[e][k] * w1c[k];
    sH1[e][c] = fmaxf(acc, 0.0f);
  }
  __syncthreads();
  for (int e = half; e < EE; e += 2) {
    float acc = b2c;
#pragma unroll
    for (int k = 0; k < 64; ++k) acc += sH1[e][k] * w2c[k];
    sH2[e][c] = fmaxf(acc, 0.0f);
  }
  __syncthreads();
  float mx = -1e30f;
  for (int e = 0; e < EE; ++e) {
    if (sValid[e]) {
      float acc = b3c;
#pragma unroll
      for (int k = 0; k < 64; ++k) acc += sH2[e][k] * w3c[k];
      mx = fmaxf(mx, acc);
    }
  }
  outX[(size_t)cs * 128 + tid] = mx;
}

extern "C" void kernel_launch(void* const* d_in, const int* in_sizes, int n_in,
                              void* d_out, int out_size, void* d_ws, size_t ws_size,
                              hipStream_t stream) {
  const float* x = (const float*)d_in[0];
  const float* pos = (const float*)d_in[1];
  const float* W1 = (const float*)d_in[3];
  const float* b1 = (const float*)d_in[4];
  const float* W2 = (const float*)d_in[5];
  const float* b2 = (const float*)d_in[6];
  const float* W3 = (const float*)d_in[7];
  const float* b3 = (const float*)d_in[8];

  float* out = (float*)d_out;
  float* outX = out;                               // [B*S,128]
  float* outC = out + (size_t)BB * SS * 128;       // [B*S,3]
  float* outB = outC + (size_t)BB * SS * 3;        // [B*S]

  float4* cellpts = (float4*)d_ws;                         // BB*NN float4
  float4* bboxLo = cellpts + (size_t)BB * NN;              // BB*256
  float4* bboxHi = bboxLo + BB * NCHUNK;                   // BB*256
  int* idx = (int*)(bboxHi + BB * NCHUNK);                 // BB*SS
  int* nbr = idx + BB * SS;                                // BB*SS*KK
  int* cnt = nbr + (size_t)BB * SS * KK;                   // BB*SS

  hipLaunchKernelGGL(bin_kernel, dim3(BB), dim3(512), 0, stream, pos, cellpts, bboxLo, bboxHi);
  hipLaunchKernelGGL(fps_kernel, dim3(BB), dim3(FPS_T), 0, stream, pos, cellpts, bboxLo, bboxHi, idx);
  hipLaunchKernelGGL(ballq_kernel, dim3(BB * SS / 4), dim3(256), 0, stream,
                     pos, idx, nbr, cnt, outC, outB);
  hipLaunchKernelGGL(mlp_kernel, dim3(BB * SS), dim3(128), 0, stream,
                     x, pos, nbr, cnt, W1, b1, W2, b2, W3, b3, outC, outX);
}

// Round 5
// 4613.843 us; speedup vs baseline: 1.2818x; 1.0328x over previous
//
#include <hip/hip_runtime.h>
#include <cstdint>
#include <cstddef>

#define BB 2
#define NN 16384
#define SS 4096
#define KK 32
#define FIN 16
#define R2C 0.01f
#define NCHUNK 256   // chunks = 64-slot ranges of the Morton-cell-sorted point array

typedef unsigned long long u64;

// ---------------- fused 32-bit DPP chains (1 instr/step after GCNDPPCombine) ----
// update_dpp(old=own, src=own): shifted-in lanes keep own value -> idempotent.
template <int CTRL>
__device__ __forceinline__ float fstep(float k) {
  const int n = __builtin_amdgcn_update_dpp(__float_as_int(k), __float_as_int(k),
                                            CTRL, 0xf, 0xf, false);
  return fmaxf(k, __int_as_float(n));  // -> v_max_f32_dpp
}
__device__ __forceinline__ float fchain(float k) {
  k = fstep<0x111>(k);  // row_shr:1
  k = fstep<0x112>(k);  // row_shr:2
  k = fstep<0x114>(k);  // row_shr:4
  k = fstep<0x118>(k);  // row_shr:8
  k = fstep<0x142>(k);  // row_bcast15
  k = fstep<0x143>(k);  // row_bcast31
  return k;             // lane 63 holds the wave max
}
template <int CTRL>
__device__ __forceinline__ unsigned int ustep(unsigned int k) {
  const unsigned int n = (unsigned int)__builtin_amdgcn_update_dpp(
      (int)k, (int)k, CTRL, 0xf, 0xf, false);
  return k > n ? k : n;  // -> v_max_u32_dpp
}
__device__ __forceinline__ unsigned int uchain(unsigned int k) {
  k = ustep<0x111>(k);
  k = ustep<0x112>(k);
  k = ustep<0x114>(k);
  k = ustep<0x118>(k);
  k = ustep<0x142>(k);
  k = ustep<0x143>(k);
  return k;             // lane 63 holds the wave max
}

// ---------------- f64-packed-key DPP wave max (phase C only, proven r0) --------
// keys are (f32bits(dmin)<<32)|rank: high bit 0 -> positive finite double, so
// f64 ordering == u64 ordering; one v_max_f64 replaces cmp+cndmask per step.
template <int CTRL>
__device__ __forceinline__ double kstep64(double k) {
  const u64 kb = (u64)__double_as_longlong(k);
  const int lo = (int)(unsigned int)kb;
  const int hi = (int)(unsigned int)(kb >> 32);
  const int nlo = __builtin_amdgcn_update_dpp(lo, lo, CTRL, 0xf, 0xf, false);
  const int nhi = __builtin_amdgcn_update_dpp(hi, hi, CTRL, 0xf, 0xf, false);
  const double nk = __longlong_as_double(
      (long long)(((u64)(unsigned int)nhi << 32) | (unsigned int)nlo));
  return fmax(k, nk);
}
__device__ __forceinline__ double kchain64(double k) {
  k = kstep64<0x111>(k);
  k = kstep64<0x112>(k);
  k = kstep64<0x114>(k);
  k = kstep64<0x118>(k);
  k = kstep64<0x142>(k);
  k = kstep64<0x143>(k);
  return k;  // lane 63 holds the wave max
}

// ---------------- binning: counting-sort points into Morton-ordered cells ----------------
__device__ __forceinline__ int part3(int x) {  // 3 bits -> bits 0,3,6
  return (x & 1) | ((x & 2) << 2) | ((x & 4) << 4);
}

__global__ __launch_bounds__(512) void bin_kernel(const float* __restrict__ pos,
                                                  float4* __restrict__ cellpts,
                                                  float4* __restrict__ bboxLo,
                                                  float4* __restrict__ bboxHi) {
  const int b = blockIdx.x, t = threadIdx.x;
  const float* __restrict__ p = pos + (size_t)b * NN * 3;
  __shared__ int hist[512], sA[512], sB[512];
  hist[t] = 0;
  __syncthreads();
  int cidc[NN / 512];  // 32 per thread
#pragma unroll
  for (int m = 0; m < NN / 512; ++m) {
    const int i = m * 512 + t;
    const float x = p[i * 3 + 0], y = p[i * 3 + 1], z = p[i * 3 + 2];
    const int cx = min(7, (int)(x * 8.0f));
    const int cy = min(7, (int)(y * 8.0f));
    const int cz = min(7, (int)(z * 8.0f));
    const int cid = part3(cx) | (part3(cy) << 1) | (part3(cz) << 2);  // Morton
    cidc[m] = cid;
    atomicAdd(&hist[cid], 1);
  }
  __syncthreads();
  sA[t] = hist[t];
  __syncthreads();
  int* src = sA;
  int* dst = sB;
  for (int off = 1; off < 512; off <<= 1) {
    int v = src[t];
    if (t >= off) v += src[t - off];
    dst[t] = v;
    __syncthreads();
    int* tmp = src; src = dst; dst = tmp;
  }
  const int excl = (t == 0) ? 0 : src[t - 1];
  __syncthreads();
  hist[t] = excl;
  __syncthreads();
#pragma unroll
  for (int m = 0; m < NN / 512; ++m) {
    const int i = m * 512 + t;
    const int slot = atomicAdd(&hist[cidc[m]], 1);
    cellpts[(size_t)b * NN + slot] =
        make_float4(p[i * 3 + 0], p[i * 3 + 1], p[i * 3 + 2], __int_as_float(i));
  }
  __threadfence_block();
  __syncthreads();
  if (t < NCHUNK) {
    float4 lo = make_float4(1e30f, 1e30f, 1e30f, 0.0f);
    float4 hi = make_float4(-1e30f, -1e30f, -1e30f, 0.0f);
    for (int k = 0; k < 64; ++k) {
      const float4 q = cellpts[(size_t)b * NN + t * 64 + k];
      lo.x = fminf(lo.x, q.x); lo.y = fminf(lo.y, q.y); lo.z = fminf(lo.z, q.z);
      hi.x = fmaxf(hi.x, q.x); hi.y = fmaxf(hi.y, q.y); hi.z = fmaxf(hi.z, q.z);
    }
    bboxLo[b * NCHUNK + t] = lo;
    bboxHi[b * NCHUNK + t] = hi;
  }
}

// ---------------- FPS: one 1024-thread block (16 waves) per batch ----------------
// Exact AABB-pruned FPS, r0 sync structure (ONE barrier/iter, double-buffered
// u64 keys). r4/r5: dmin is fully REGISTER-RESIDENT (dmn[16] per lane — r3
// made sDmin wave-private, so the 64 KB LDS array and its ~160 LDS ops/iter
// are deleted). Per-chunk key results are gathered via readlane + inline-asm
// v_writelane_b32 (builtin not exposed on this ROCm; lane index is a literal
// via macro stamping) into one (vhi,vlo) pair and written with a SINGLE
// ds_write_b64 by lanes 0-15 per iteration (also absorbing phase A's carry
// write: vhi/vlo init from kOwn). Phase C reads keys as 2x ds_read_b128 and
// fetches winner coords via the rank word's low 14 bits (= sorted slot) with
// one uniform 16B load of cp[slot].
// Key format (dminbits<<32)|((16383-pid)<<14|chunk<<6|lane) == r3 (proven):
// exact (dmin desc, pid asc) order; decode fi = 16383-(lo>>14).
#define FPS_T 1024
#define FPS_NW 16

__global__ __launch_bounds__(FPS_T, 1) void fps_kernel(const float* __restrict__ pos,
                                                       const float4* __restrict__ cellpts,
                                                       const float4* __restrict__ bboxLo,
                                                       const float4* __restrict__ bboxHi,
                                                       int* __restrict__ idx_out) {
  const int b = blockIdx.x;
  const int t = threadIdx.x;
  const int wid = t >> 6;   // 0..15
  const int lane = t & 63;
  const float* __restrict__ p = pos + (size_t)b * NN * 3;
  const float4* __restrict__ cp = cellpts + (size_t)b * NN;

  __shared__ __align__(16) u64 sKey[2][NCHUNK];  // double-buffered chunk keys (4 KB)

  const int cown = ((lane & 15) << 4) | wid;  // owned chunk (real for lane<16)
  const int slotOwn = (wid << 4) | (lane & 15);
  const float4 blo = bboxLo[b * NCHUNK + cown];
  const float4 bhi = bboxHi[b * NCHUNK + cown];

  // this wave's 16 owned chunks: coords + encoded rank + dmin, ALL in registers.
  // rank = (16383-pid)<<14 | chunk<<6 | lane : low 14 bits == sorted slot.
  float px[16], py[16], pz[16], dmn[16];
  unsigned int rp[16];
#pragma unroll
  for (int cc = 0; cc < 16; ++cc) {
    const int c = (cc << 4) | wid;
    const float4 q = cp[(size_t)((c << 6) + lane)];
    px[cc] = q.x; py[cc] = q.y; pz[cc] = q.z;
    const unsigned int pid = (unsigned int)__float_as_int(q.w);
    rp[cc] = ((16383u - pid) << 14) | ((unsigned int)c << 6) | (unsigned int)lane;
    dmn[cc] = 1e10f;
  }

  const u64 initKey = ((u64)(unsigned int)__float_as_int(1e30f) << 32);
  if (t < NCHUNK) sKey[0][t] = initKey;
  if (t == 0) idx_out[b * SS + 0] = 0;
  float lx = p[0], ly = p[1], lz = p[2];
  u64 kOwn = initKey;  // key of this lane's owned slot, carried across iters
  __syncthreads();

  int buf = 0;

  for (int it = 1; it < SS; ++it) {
    // ---- A: test owned chunks (pure VALU, boxes + key in regs) ----
    const float mvOwn = __int_as_float((int)(unsigned int)(kOwn >> 32));
    const float ax = fmaxf(fmaxf(blo.x - lx, lx - bhi.x), 0.0f);
    const float ay = fmaxf(fmaxf(blo.y - ly, ly - bhi.y), 0.0f);
    const float az = fmaxf(fmaxf(blo.z - lz, lz - bhi.z), 0.0f);
    const float bl2 = ax * ax + ay * ay + az * az;
    // skip iff conservative lower bound exceeds chunk max dmin: then
    // min(dmin_j, d_j) == dmin_j exactly for every member (bit-exact skip).
    const bool act = (lane < 16) && !(bl2 * 0.99999f > mvOwn);
    const unsigned int mm = (unsigned int)__ballot(act);  // uniform, low 16 bits

    // carry defaults: inactive owned chunks keep their old key
    int vhi = (int)(unsigned int)(kOwn >> 32);
    int vlo = (int)(unsigned int)kOwn;

    // ---- B: predicated unroll over the 16 owned chunks, zero LDS traffic ----
    // (macro-stamped so the writelane lane index is a literal immediate)
#define BODY(cc)                                                                 \
    if (mm & (1u << cc)) {                                                       \
      const float dx = px[cc] - lx, dy = py[cc] - ly, dz = pz[cc] - lz;          \
      const float d = __fadd_rn(__fadd_rn(__fmul_rn(dx, dx), __fmul_rn(dy, dy)), \
                                __fmul_rn(dz, dz));                              \
      const float nd = fminf(dmn[cc], d);                                        \
      dmn[cc] = nd;                                                              \
      const float cm = fchain(nd); /* lane 63: chunk max */                      \
      const int cmb = __builtin_amdgcn_readlane(__float_as_int(cm), 63);         \
      unsigned int tt = (nd == __int_as_float(cmb)) ? rp[cc] : 0u;               \
      tt = uchain(tt); /* lane 63: max rank == lowest pid among tied */          \
      const int tts = __builtin_amdgcn_readlane((int)tt, 63);                    \
      asm("v_writelane_b32 %0, %1, " #cc : "+v"(vhi) : "s"(cmb));                \
      asm("v_writelane_b32 %0, %1, " #cc : "+v"(vlo) : "s"(tts));                \
    }
    BODY(0) BODY(1) BODY(2) BODY(3) BODY(4) BODY(5) BODY(6) BODY(7)
    BODY(8) BODY(9) BODY(10) BODY(11) BODY(12) BODY(13) BODY(14) BODY(15)
#undef BODY

    // ONE ds_write_b64 covering all 16 owned slots (new keys + carries)
    if (lane < 16)
      sKey[buf ^ 1][slotOwn] = ((u64)(unsigned int)vhi << 32) | (unsigned int)vlo;
    __syncthreads();  // the ONLY barrier per iteration
    buf ^= 1;

    // ---- C: global winner over 256 packed chunk keys (all waves, redundant) ----
    kOwn = sKey[buf][slotOwn];  // hoisted for next iteration's A (stride-1)
    const ulonglong2 ka = *(const ulonglong2*)&sKey[buf][2 * lane];
    const ulonglong2 kb = *(const ulonglong2*)&sKey[buf][128 + 2 * lane];
    double bk = fmax(fmax(__longlong_as_double((long long)ka.x),
                          __longlong_as_double((long long)ka.y)),
                     fmax(__longlong_as_double((long long)kb.x),
                          __longlong_as_double((long long)kb.y)));
    bk = kchain64(bk);
    const unsigned int lo63 = (unsigned int)__builtin_amdgcn_readlane(
        (int)(unsigned int)(u64)__double_as_longlong(bk), 63);
    const int fi = 16383 - (int)(lo63 >> 14);  // decode winning original index
    if (t == 0) idx_out[b * SS + it] = fi;
    // winner coords via sorted slot (low 14 bits of rank): ONE uniform 16B load
    const int slot = (int)(lo63 & 0x3FFFu);
    const float4 wq = cp[(size_t)slot];
    lx = wq.x;
    ly = wq.y;
    lz = wq.z;
  }
}

// ---------------- Ball query: one wave per centroid ----------------
__global__ __launch_bounds__(256) void ballq_kernel(const float* __restrict__ pos,
                                                    const int* __restrict__ idx,
                                                    int* __restrict__ nbr,
                                                    int* __restrict__ cnt,
                                                    float* __restrict__ outC,
                                                    float* __restrict__ outB) {
  const int cs = blockIdx.x * 4 + (threadIdx.x >> 6);
  const int lane = threadIdx.x & 63;
  const int b = cs >> 12;           // S = 4096
  const int s = cs & (SS - 1);
  const float* __restrict__ p = pos + (size_t)b * NN * 3;
  const int ci = idx[cs];
  const float cx = p[ci * 3 + 0], cy = p[ci * 3 + 1], cz = p[ci * 3 + 2];
  // remove_self_loops: global src b*N+i == global dst b*S+s -> only b==0, i==s
  const int excl = (b == 0) ? s : -1;
  int count = 0;
  for (int tile = 0; tile < NN / 64; ++tile) {
    const int i = tile * 64 + lane;
    const float dx = cx - p[i * 3 + 0];
    const float dy = cy - p[i * 3 + 1];
    const float dz = cz - p[i * 3 + 2];
    const float d2 = __fadd_rn(__fadd_rn(__fmul_rn(dx, dx), __fmul_rn(dy, dy)), __fmul_rn(dz, dz));
    const bool in = (d2 <= R2C) && (i != excl);
    const unsigned long long m = __ballot(in);
    if (in) {
      const int rank = count + (int)__popcll(m & ((1ull << lane) - 1ull));
      if (rank < KK) nbr[cs * KK + rank] = i;
    }
    count += (int)__popcll(m);
    if (count >= KK) break;
  }
  if (lane == 0) {
    cnt[cs] = count < KK ? count : KK;
    outC[cs * 3 + 0] = cx;
    outC[cs * 3 + 1] = cy;
    outC[cs * 3 + 2] = cz;
    outB[cs] = (float)b;
  }
}

// ---------------- MLP + max: one block (128 thr) per centroid ----------------
#define EE 33
__global__ __launch_bounds__(128) void mlp_kernel(const float* __restrict__ x,
                                                  const float* __restrict__ pos,
                                                  const int* __restrict__ nbr,
                                                  const int* __restrict__ cnt,
                                                  const float* __restrict__ W1,
                                                  const float* __restrict__ b1,
                                                  const float* __restrict__ W2,
                                                  const float* __restrict__ b2,
                                                  const float* __restrict__ W3,
                                                  const float* __restrict__ b3,
                                                  const float* __restrict__ outC,
                                                  float* __restrict__ outX) {
  __shared__ float sF[EE][20];
  __shared__ float sH1[EE][64];
  __shared__ float sH2[EE][64];
  __shared__ int sValid[EE];

  const int cs = blockIdx.x;
  const int tid = threadIdx.x;
  const int b = cs >> 12;
  const int c = tid & 63;
  const int half = tid >> 6;

  float w1c[19], w2c[64], w3c[64];
#pragma unroll
  for (int k = 0; k < 19; ++k) w1c[k] = W1[k * 64 + c];
#pragma unroll
  for (int k = 0; k < 64; ++k) w2c[k] = W2[k * 64 + c];
#pragma unroll
  for (int k = 0; k < 64; ++k) w3c[k] = W3[k * 128 + tid];
  const float b1c = b1[c], b2c = b2[c], b3c = b3[tid];

  if (tid < EE) {
    const float ccx = outC[cs * 3 + 0], ccy = outC[cs * 3 + 1], ccz = outC[cs * 3 + 2];
    int row;
    bool valid;
    if (tid < KK) {
      const int cn = cnt[cs];
      valid = tid < cn;
      const int j = valid ? nbr[cs * KK + tid] : 0;
      row = b * NN + j;
    } else {
      // PyG add_self_loops quirk: src is flat point index dflat = b*S+s = cs
      valid = true;
      row = cs;
    }
    for (int f = 0; f < FIN; ++f) sF[tid][f] = x[(size_t)row * FIN + f];
    sF[tid][16] = pos[(size_t)row * 3 + 0] - ccx;
    sF[tid][17] = pos[(size_t)row * 3 + 1] - ccy;
    sF[tid][18] = pos[(size_t)row * 3 + 2] - ccz;
    sValid[tid] = valid ? 1 : 0;
  }
  __syncthreads();
  for (int e = half; e < EE; e += 2) {
    float acc = b1c;
#pragma unroll
    for (int k = 0; k < 19; ++k) acc += sF[e][k] * w1c[k];
    sH1[e][c] = fmaxf(acc, 0.0f);
  }
  __syncthreads();
  for (int e = half; e < EE; e += 2) {
    float acc = b2c;
#pragma unroll
    for (int k = 0; k < 64; ++k) acc += sH1[e][k] * w2c[k];
    sH2[e][c] = fmaxf(acc, 0.0f);
  }
  __syncthreads();
  float mx = -1e30f;
  for (int e = 0; e < EE; ++e) {
    if (sValid[e]) {
      float acc = b3c;
#pragma unroll
      for (int k = 0; k < 64; ++k) acc += sH2[e][k] * w3c[k];
      mx = fmaxf(mx, acc);
    }
  }
  outX[(size_t)cs * 128 + tid] = mx;
}

extern "C" void kernel_launch(void* const* d_in, const int* in_sizes, int n_in,
                              void* d_out, int out_size, void* d_ws, size_t ws_size,
                              hipStream_t stream) {
  const float* x = (const float*)d_in[0];
  const float* pos = (const float*)d_in[1];
  const float* W1 = (const float*)d_in[3];
  const float* b1 = (const float*)d_in[4];
  const float* W2 = (const float*)d_in[5];
  const float* b2 = (const float*)d_in[6];
  const float* W3 = (const float*)d_in[7];
  const float* b3 = (const float*)d_in[8];

  float* out = (float*)d_out;
  float* outX = out;                               // [B*S,128]
  float* outC = out + (size_t)BB * SS * 128;       // [B*S,3]
  float* outB = outC + (size_t)BB * SS * 3;        // [B*S]

  float4* cellpts = (float4*)d_ws;                         // BB*NN float4
  float4* bboxLo = cellpts + (size_t)BB * NN;              // BB*256
  float4* bboxHi = bboxLo + BB * NCHUNK;                   // BB*256
  int* idx = (int*)(bboxHi + BB * NCHUNK);                 // BB*SS
  int* nbr = idx + BB * SS;                                // BB*SS*KK
  int* cnt = nbr + (size_t)BB * SS * KK;                   // BB*SS

  hipLaunchKernelGGL(bin_kernel, dim3(BB), dim3(512), 0, stream, pos, cellpts, bboxLo, bboxHi);
  hipLaunchKernelGGL(fps_kernel, dim3(BB), dim3(FPS_T), 0, stream, pos, cellpts, bboxLo, bboxHi, idx);
  hipLaunchKernelGGL(ballq_kernel, dim3(BB * SS / 4), dim3(256), 0, stream,
                     pos, idx, nbr, cnt, outC, outB);
  hipLaunchKernelGGL(mlp_kernel, dim3(BB * SS), dim3(128), 0, stream,
                     x, pos, nbr, cnt, W1, b1, W2, b2, W3, b3, outC, outX);
}

// Round 6
// 4332.515 us; speedup vs baseline: 1.3650x; 1.0649x over previous
//
#include <hip/hip_runtime.h>
#include <cstdint>
#include <cstddef>

#define BB 2
#define NN 16384
#define SS 4096
#define KK 32
#define FIN 16
#define R2C 0.01f
#define NCHUNK 256   // chunks = 64-slot ranges of the Morton-cell-sorted point array

typedef unsigned long long u64;

// ---------------- fused 32-bit DPP chains (1 instr/step after GCNDPPCombine) ----
// update_dpp(old=own, src=own): shifted-in lanes keep own value -> idempotent.
template <int CTRL>
__device__ __forceinline__ float fstep(float k) {
  const int n = __builtin_amdgcn_update_dpp(__float_as_int(k), __float_as_int(k),
                                            CTRL, 0xf, 0xf, false);
  return fmaxf(k, __int_as_float(n));  // -> v_max_f32_dpp
}
__device__ __forceinline__ float fchain(float k) {
  k = fstep<0x111>(k);  // row_shr:1
  k = fstep<0x112>(k);  // row_shr:2
  k = fstep<0x114>(k);  // row_shr:4
  k = fstep<0x118>(k);  // row_shr:8
  k = fstep<0x142>(k);  // row_bcast15
  k = fstep<0x143>(k);  // row_bcast31
  return k;             // lane 63 holds the wave max
}
template <int CTRL>
__device__ __forceinline__ unsigned int ustep(unsigned int k) {
  const unsigned int n = (unsigned int)__builtin_amdgcn_update_dpp(
      (int)k, (int)k, CTRL, 0xf, 0xf, false);
  return k > n ? k : n;  // -> v_max_u32_dpp
}
__device__ __forceinline__ unsigned int uchain(unsigned int k) {
  k = ustep<0x111>(k);
  k = ustep<0x112>(k);
  k = ustep<0x114>(k);
  k = ustep<0x118>(k);
  k = ustep<0x142>(k);
  k = ustep<0x143>(k);
  return k;             // lane 63 holds the wave max
}

// ---------------- f64-packed-key DPP wave max (phase C only, proven r0) --------
// keys are (f32bits(dmin)<<32)|rank: high bit 0 -> positive finite double, so
// f64 ordering == u64 ordering; one v_max_f64 replaces cmp+cndmask per step.
template <int CTRL>
__device__ __forceinline__ double kstep64(double k) {
  const u64 kb = (u64)__double_as_longlong(k);
  const int lo = (int)(unsigned int)kb;
  const int hi = (int)(unsigned int)(kb >> 32);
  const int nlo = __builtin_amdgcn_update_dpp(lo, lo, CTRL, 0xf, 0xf, false);
  const int nhi = __builtin_amdgcn_update_dpp(hi, hi, CTRL, 0xf, 0xf, false);
  const double nk = __longlong_as_double(
      (long long)(((u64)(unsigned int)nhi << 32) | (unsigned int)nlo));
  return fmax(k, nk);
}
__device__ __forceinline__ double kchain64(double k) {
  k = kstep64<0x111>(k);
  k = kstep64<0x112>(k);
  k = kstep64<0x114>(k);
  k = kstep64<0x118>(k);
  k = kstep64<0x142>(k);
  k = kstep64<0x143>(k);
  return k;  // lane 63 holds the wave max
}

// ---------------- binning: counting-sort points into Morton-ordered cells ----------------
__device__ __forceinline__ int part3(int x) {  // 3 bits -> bits 0,3,6
  return (x & 1) | ((x & 2) << 2) | ((x & 4) << 4);
}

__global__ __launch_bounds__(512) void bin_kernel(const float* __restrict__ pos,
                                                  float4* __restrict__ cellpts,
                                                  float4* __restrict__ bboxLo,
                                                  float4* __restrict__ bboxHi) {
  const int b = blockIdx.x, t = threadIdx.x;
  const float* __restrict__ p = pos + (size_t)b * NN * 3;
  __shared__ int hist[512], sA[512], sB[512];
  hist[t] = 0;
  __syncthreads();
  int cidc[NN / 512];  // 32 per thread
#pragma unroll
  for (int m = 0; m < NN / 512; ++m) {
    const int i = m * 512 + t;
    const float x = p[i * 3 + 0], y = p[i * 3 + 1], z = p[i * 3 + 2];
    const int cx = min(7, (int)(x * 8.0f));
    const int cy = min(7, (int)(y * 8.0f));
    const int cz = min(7, (int)(z * 8.0f));
    const int cid = part3(cx) | (part3(cy) << 1) | (part3(cz) << 2);  // Morton
    cidc[m] = cid;
    atomicAdd(&hist[cid], 1);
  }
  __syncthreads();
  sA[t] = hist[t];
  __syncthreads();
  int* src = sA;
  int* dst = sB;
  for (int off = 1; off < 512; off <<= 1) {
    int v = src[t];
    if (t >= off) v += src[t - off];
    dst[t] = v;
    __syncthreads();
    int* tmp = src; src = dst; dst = tmp;
  }
  const int excl = (t == 0) ? 0 : src[t - 1];
  __syncthreads();
  hist[t] = excl;
  __syncthreads();
#pragma unroll
  for (int m = 0; m < NN / 512; ++m) {
    const int i = m * 512 + t;
    const int slot = atomicAdd(&hist[cidc[m]], 1);
    cellpts[(size_t)b * NN + slot] =
        make_float4(p[i * 3 + 0], p[i * 3 + 1], p[i * 3 + 2], __int_as_float(i));
  }
  __threadfence_block();
  __syncthreads();
  if (t < NCHUNK) {
    float4 lo = make_float4(1e30f, 1e30f, 1e30f, 0.0f);
    float4 hi = make_float4(-1e30f, -1e30f, -1e30f, 0.0f);
    for (int k = 0; k < 64; ++k) {
      const float4 q = cellpts[(size_t)b * NN + t * 64 + k];
      lo.x = fminf(lo.x, q.x); lo.y = fminf(lo.y, q.y); lo.z = fminf(lo.z, q.z);
      hi.x = fmaxf(hi.x, q.x); hi.y = fmaxf(hi.y, q.y); hi.z = fmaxf(hi.z, q.z);
    }
    bboxLo[b * NCHUNK + t] = lo;
    bboxHi[b * NCHUNK + t] = hi;
  }
}

// ---------------- FPS: one 1024-thread block (16 waves) per batch ----------------
// Exact AABB-pruned FPS, r0 sync structure (ONE barrier/iter, double-buffered
// u64 keys). dmin fully register-resident (dmn[16]); per-chunk results gathered
// via readlane + inline-asm v_writelane into one (vhi,vlo) pair; ONE
// ds_write_b64 per wave per iteration. r6: (1) tie-break fast path — after the
// fused f32-max chain, ballot(nd==max); when a single lane holds the max
// (overwhelmingly common, exact test), its rank is fetched with ONE
// variable-lane readlane (SALU ff1), skipping the 6-step uchain + cmp/cndmask;
// genuine ties fall back to the proven uchain (bit-identical either way).
// (2) kOwn carried in registers (kHi,kLo == the pair lanes 0-15 just wrote),
// dropping phase C's kOwn ds_read.
// Key format (dminbits<<32)|((16383-pid)<<14|chunk<<6|lane) == r3 (proven):
// exact (dmin desc, pid asc) order; decode fi = 16383-(lo>>14); low 14 bits of
// rank == sorted slot -> winner coords via one uniform 16B load of cp[slot].
#define FPS_T 1024
#define FPS_NW 16

__global__ __launch_bounds__(FPS_T, 1) void fps_kernel(const float* __restrict__ pos,
                                                       const float4* __restrict__ cellpts,
                                                       const float4* __restrict__ bboxLo,
                                                       const float4* __restrict__ bboxHi,
                                                       int* __restrict__ idx_out) {
  const int b = blockIdx.x;
  const int t = threadIdx.x;
  const int wid = t >> 6;   // 0..15
  const int lane = t & 63;
  const float* __restrict__ p = pos + (size_t)b * NN * 3;
  const float4* __restrict__ cp = cellpts + (size_t)b * NN;

  __shared__ __align__(16) u64 sKey[2][NCHUNK];  // double-buffered chunk keys (4 KB)

  const int cown = ((lane & 15) << 4) | wid;  // owned chunk (real for lane<16)
  const int slotOwn = (wid << 4) | (lane & 15);
  const float4 blo = bboxLo[b * NCHUNK + cown];
  const float4 bhi = bboxHi[b * NCHUNK + cown];

  // this wave's 16 owned chunks: coords + encoded rank + dmin, ALL in registers.
  // rank = (16383-pid)<<14 | chunk<<6 | lane : low 14 bits == sorted slot.
  float px[16], py[16], pz[16], dmn[16];
  unsigned int rp[16];
#pragma unroll
  for (int cc = 0; cc < 16; ++cc) {
    const int c = (cc << 4) | wid;
    const float4 q = cp[(size_t)((c << 6) + lane)];
    px[cc] = q.x; py[cc] = q.y; pz[cc] = q.z;
    const unsigned int pid = (unsigned int)__float_as_int(q.w);
    rp[cc] = ((16383u - pid) << 14) | ((unsigned int)c << 6) | (unsigned int)lane;
    dmn[cc] = 1e10f;
  }

  const u64 initKey = ((u64)(unsigned int)__float_as_int(1e30f) << 32);
  if (t < NCHUNK) sKey[0][t] = initKey;
  if (t == 0) idx_out[b * SS + 0] = 0;
  float lx = p[0], ly = p[1], lz = p[2];
  int kHi = __float_as_int(1e30f);  // owned-slot key, carried across iterations
  int kLo = 0;
  __syncthreads();

  int buf = 0;

  for (int it = 1; it < SS; ++it) {
    // ---- A: test owned chunks (pure VALU, boxes + key in regs) ----
    const float mvOwn = __int_as_float(kHi);
    const float ax = fmaxf(fmaxf(blo.x - lx, lx - bhi.x), 0.0f);
    const float ay = fmaxf(fmaxf(blo.y - ly, ly - bhi.y), 0.0f);
    const float az = fmaxf(fmaxf(blo.z - lz, lz - bhi.z), 0.0f);
    const float bl2 = ax * ax + ay * ay + az * az;
    // skip iff conservative lower bound exceeds chunk max dmin: then
    // min(dmin_j, d_j) == dmin_j exactly for every member (bit-exact skip).
    const bool act = (lane < 16) && !(bl2 * 0.99999f > mvOwn);
    const unsigned int mm = (unsigned int)__ballot(act);  // uniform, low 16 bits

    // carry defaults: inactive owned chunks keep their old key
    int vhi = kHi;
    int vlo = kLo;

    // ---- B: predicated unroll over the 16 owned chunks, zero LDS traffic ----
    // (macro-stamped so the writelane lane index is a literal immediate)
#define BODY(cc)                                                                 \
    if (mm & (1u << cc)) {                                                       \
      const float dx = px[cc] - lx, dy = py[cc] - ly, dz = pz[cc] - lz;          \
      const float d = __fadd_rn(__fadd_rn(__fmul_rn(dx, dx), __fmul_rn(dy, dy)), \
                                __fmul_rn(dz, dz));                              \
      const float nd = fminf(dmn[cc], d);                                        \
      dmn[cc] = nd;                                                              \
      const float cm = fchain(nd); /* lane 63: chunk max */                      \
      const int cmb = __builtin_amdgcn_readlane(__float_as_int(cm), 63);         \
      const u64 tmask = __ballot(nd == __int_as_float(cmb));                     \
      int tts;                                                                   \
      if (__builtin_expect((tmask & (tmask - 1)) != 0, 0)) { /* true tie */      \
        unsigned int tt = (nd == __int_as_float(cmb)) ? rp[cc] : 0u;             \
        tt = uchain(tt); /* lane 63: max rank == lowest pid among tied */        \
        tts = __builtin_amdgcn_readlane((int)tt, 63);                            \
      } else { /* unique argmax lane: one variable-lane readlane */              \
        tts = __builtin_amdgcn_readlane((int)rp[cc],                             \
                                        (int)__builtin_ctzll(tmask));            \
      }                                                                          \
      asm("v_writelane_b32 %0, %1, " #cc : "+v"(vhi) : "s"(cmb));                \
      asm("v_writelane_b32 %0, %1, " #cc : "+v"(vlo) : "s"(tts));                \
    }
    BODY(0) BODY(1) BODY(2) BODY(3) BODY(4) BODY(5) BODY(6) BODY(7)
    BODY(8) BODY(9) BODY(10) BODY(11) BODY(12) BODY(13) BODY(14) BODY(15)
#undef BODY

    // ONE ds_write_b64 covering all 16 owned slots (new keys + carries)
    if (lane < 16)
      sKey[buf ^ 1][slotOwn] = ((u64)(unsigned int)vhi << 32) | (unsigned int)vlo;
    kHi = vhi;  // register carry of the owned-slot key (valid where used)
    kLo = vlo;
    __syncthreads();  // the ONLY barrier per iteration
    buf ^= 1;

    // ---- C: global winner over 256 packed chunk keys (all waves, redundant) ----
    const ulonglong2 ka = *(const ulonglong2*)&sKey[buf][2 * lane];
    const ulonglong2 kb = *(const ulonglong2*)&sKey[buf][128 + 2 * lane];
    double bk = fmax(fmax(__longlong_as_double((long long)ka.x),
                          __longlong_as_double((long long)ka.y)),
                     fmax(__longlong_as_double((long long)kb.x),
                          __longlong_as_double((long long)kb.y)));
    bk = kchain64(bk);
    const unsigned int lo63 = (unsigned int)__builtin_amdgcn_readlane(
        (int)(unsigned int)(u64)__double_as_longlong(bk), 63);
    const int fi = 16383 - (int)(lo63 >> 14);  // decode winning original index
    if (t == 0) idx_out[b * SS + it] = fi;
    // winner coords via sorted slot (low 14 bits of rank): ONE uniform 16B load
    const int slot = (int)(lo63 & 0x3FFFu);
    const float4 wq = cp[(size_t)slot];
    lx = wq.x;
    ly = wq.y;
    lz = wq.z;
  }
}

// ---------------- Ball query: one wave per centroid ----------------
__global__ __launch_bounds__(256) void ballq_kernel(const float* __restrict__ pos,
                                                    const int* __restrict__ idx,
                                                    int* __restrict__ nbr,
                                                    int* __restrict__ cnt,
                                                    float* __restrict__ outC,
                                                    float* __restrict__ outB) {
  const int cs = blockIdx.x * 4 + (threadIdx.x >> 6);
  const int lane = threadIdx.x & 63;
  const int b = cs >> 12;           // S = 4096
  const int s = cs & (SS - 1);
  const float* __restrict__ p = pos + (size_t)b * NN * 3;
  const int ci = idx[cs];
  const float cx = p[ci * 3 + 0], cy = p[ci * 3 + 1], cz = p[ci * 3 + 2];
  // remove_self_loops: global src b*N+i == global dst b*S+s -> only b==0, i==s
  const int excl = (b == 0) ? s : -1;
  int count = 0;
  for (int tile = 0; tile < NN / 64; ++tile) {
    const int i = tile * 64 + lane;
    const float dx = cx - p[i * 3 + 0];
    const float dy = cy - p[i * 3 + 1];
    const float dz = cz - p[i * 3 + 2];
    const float d2 = __fadd_rn(__fadd_rn(__fmul_rn(dx, dx), __fmul_rn(dy, dy)), __fmul_rn(dz, dz));
    const bool in = (d2 <= R2C) && (i != excl);
    const unsigned long long m = __ballot(in);
    if (in) {
      const int rank = count + (int)__popcll(m & ((1ull << lane) - 1ull));
      if (rank < KK) nbr[cs * KK + rank] = i;
    }
    count += (int)__popcll(m);
    if (count >= KK) break;
  }
  if (lane == 0) {
    cnt[cs] = count < KK ? count : KK;
    outC[cs * 3 + 0] = cx;
    outC[cs * 3 + 1] = cy;
    outC[cs * 3 + 2] = cz;
    outB[cs] = (float)b;
  }
}

// ---------------- MLP + max: one block (128 thr) per centroid ----------------
#define EE 33
__global__ __launch_bounds__(128) void mlp_kernel(const float* __restrict__ x,
                                                  const float* __restrict__ pos,
                                                  const int* __restrict__ nbr,
                                                  const int* __restrict__ cnt,
                                                  const float* __restrict__ W1,
                                                  const float* __restrict__ b1,
                                                  const float* __restrict__ W2,
                                                  const float* __restrict__ b2,
                                                  const float* __restrict__ W3,
                                                  const float* __restrict__ b3,
                                                  const float* __restrict__ outC,
                                                  float* __restrict__ outX) {
  __shared__ float sF[EE][20];
  __shared__ float sH1[EE][64];
  __shared__ float sH2[EE][64];
  __shared__ int sValid[EE];

  const int cs = blockIdx.x;
  const int tid = threadIdx.x;
  const int b = cs >> 12;
  const int c = tid & 63;
  const int half = tid >> 6;

  float w1c[19], w2c[64], w3c[64];
#pragma unroll
  for (int k = 0; k < 19; ++k) w1c[k] = W1[k * 64 + c];
#pragma unroll
  for (int k = 0; k < 64; ++k) w2c[k] = W2[k * 64 + c];
#pragma unroll
  for (int k = 0; k < 64; ++k) w3c[k] = W3[k * 128 + tid];
  const float b1c = b1[c], b2c = b2[c], b3c = b3[tid];

  if (tid < EE) {
    const float ccx = outC[cs * 3 + 0], ccy = outC[cs * 3 + 1], ccz = outC[cs * 3 + 2];
    int row;
    bool valid;
    if (tid < KK) {
      const int cn = cnt[cs];
      valid = tid < cn;
      const int j = valid ? nbr[cs * KK + tid] : 0;
      row = b * NN + j;
    } else {
      // PyG add_self_loops quirk: src is flat point index dflat = b*S+s = cs
      valid = true;
      row = cs;
    }
    for (int f = 0; f < FIN; ++f) sF[tid][f] = x[(size_t)row * FIN + f];
    sF[tid][16] = pos[(size_t)row * 3 + 0] - ccx;
    sF[tid][17] = pos[(size_t)row * 3 + 1] - ccy;
    sF[tid][18] = pos[(size_t)row * 3 + 2] - ccz;
    sValid[tid] = valid ? 1 : 0;
  }
  __syncthreads();
  for (int e = half; e < EE; e += 2) {
    float acc = b1c;
#pragma unroll
    for (int k = 0; k < 19; ++k) acc += sF[e][k] * w1c[k];
    sH1[e][c] = fmaxf(acc, 0.0f);
  }
  __syncthreads();
  for (int e = half; e < EE; e += 2) {
    float acc = b2c;
#pragma unroll
    for (int k = 0; k < 64; ++k) acc += sH1[e][k] * w2c[k];
    sH2[e][c] = fmaxf(acc, 0.0f);
  }
  __syncthreads();
  float mx = -1e30f;
  for (int e = 0; e < EE; ++e) {
    if (sValid[e]) {
      float acc = b3c;
#pragma unroll
      for (int k = 0; k < 64; ++k) acc += sH2[e][k] * w3c[k];
      mx = fmaxf(mx, acc);
    }
  }
  outX[(size_t)cs * 128 + tid] = mx;
}

extern "C" void kernel_launch(void* const* d_in, const int* in_sizes, int n_in,
                              void* d_out, int out_size, void* d_ws, size_t ws_size,
                              hipStream_t stream) {
  const float* x = (const float*)d_in[0];
  const float* pos = (const float*)d_in[1];
  const float* W1 = (const float*)d_in[3];
  const float* b1 = (const float*)d_in[4];
  const float* W2 = (const float*)d_in[5];
  const float* b2 = (const float*)d_in[6];
  const float* W3 = (const float*)d_in[7];
  const float* b3 = (const float*)d_in[8];

  float* out = (float*)d_out;
  float* outX = out;                               // [B*S,128]
  float* outC = out + (size_t)BB * SS * 128;       // [B*S,3]
  float* outB = outC + (size_t)BB * SS * 3;        // [B*S]

  float4* cellpts = (float4*)d_ws;                         // BB*NN float4
  float4* bboxLo = cellpts + (size_t)BB * NN;              // BB*256
  float4* bboxHi = bboxLo + BB * NCHUNK;                   // BB*256
  int* idx = (int*)(bboxHi + BB * NCHUNK);                 // BB*SS
  int* nbr = idx + BB * SS;                                // BB*SS*KK
  int* cnt = nbr + (size_t)BB * SS * KK;                   // BB*SS

  hipLaunchKernelGGL(bin_kernel, dim3(BB), dim3(512), 0, stream, pos, cellpts, bboxLo, bboxHi);
  hipLaunchKernelGGL(fps_kernel, dim3(BB), dim3(FPS_T), 0, stream, pos, cellpts, bboxLo, bboxHi, idx);
  hipLaunchKernelGGL(ballq_kernel, dim3(BB * SS / 4), dim3(256), 0, stream,
                     pos, idx, nbr, cnt, outC, outB);
  hipLaunchKernelGGL(mlp_kernel, dim3(BB * SS), dim3(128), 0, stream,
                     x, pos, nbr, cnt, W1, b1, W2, b2, W3, b3, outC, outX);
}